// Round 5
// baseline (559.522 us; speedup 1.0000x reference)
//
#include <hip/hip_runtime.h>
#include <stdint.h>

#define BTOK 2048
#define HDIM 512
#define VOC  32000
#define BM 128
#define BN 128
#define BK 32
#define NKT (HDIM / BK)          // 16 K-steps
#define BLOB_E (BM * BK)         // 4096 ushorts = 8 KB per (panel, kt) blob
#define NVB (VOC / BN)           // 250
#define NRB (BTOK / BM)          // 16
#define NBLK (NVB * NRB)         // 4000

// ws layout (bytes):
//   [0, 40960)      rowacc (2048 x 5 f32)
//   [65536, ...)    bf16 blobs: s_in | t_in | s_w | t_w
#define WS_BLOB_OFF 65536
#define INB_E (BTOK * HDIM)      // 1,048,576 ushorts
#define WB_E  (VOC * HDIM)       // 16,384,000 ushorts
#define WS_NEED (WS_BLOB_OFF + (size_t)(2 * INB_E + 2 * WB_E) * 2)  // ~69.8 MB

typedef __attribute__((ext_vector_type(8))) short bf16x8;
typedef __attribute__((ext_vector_type(4))) float f32x4;

__device__ __forceinline__ unsigned short f2b(float f) {
    union { float f; uint32_t u; } x; x.f = f;
    uint32_t u = x.u;
    u += 0x7fffu + ((u >> 16) & 1u);   // RNE
    return (unsigned short)(u >> 16);
}

// ---------------------------------------------------------------------------
// Pass 1: f32 -> bf16 blobs with FULL-ADDRESS XOR swizzle pre-applied:
//   e = (r*32 + cc) ^ ((r&7)<<3)
// NOTE: X=(r&7)<<3 has bit 5, which flips the row LSB of the linear address —
// bijective. The GEMM reads with the SAME full-address XOR (R4's bug was a
// column-local XOR on the read side: +32 carry instead of row-LSB flip for
// r&7 in {5,7} -> garbage -> NaN).
// ---------------------------------------------------------------------------
__global__ __launch_bounds__(256) void convert_pack(
    const float* __restrict__ s_in, const float* __restrict__ s_w,
    const float* __restrict__ t_in, const float* __restrict__ t_w,
    unsigned short* __restrict__ blob)
{
    unsigned short* sinb = blob;
    unsigned short* tinb = blob + INB_E;
    unsigned short* swb  = blob + 2 * INB_E;
    unsigned short* twb  = blob + 2 * INB_E + WB_E;
    const int total4 = (2 * BTOK + 2 * VOC) * (HDIM / 4);
    for (int f = blockIdx.x * 256 + threadIdx.x; f < total4; f += gridDim.x * 256) {
        const int row = f >> 7;            // 128 float4 per source row
        const int c4  = f & 127;
        const float* src; unsigned short* dstb; int lrow;
        if (row < BTOK)                { src = s_in; dstb = sinb; lrow = row; }
        else if (row < BTOK + VOC)     { src = s_w;  dstb = swb;  lrow = row - BTOK; }
        else if (row < 2*BTOK + VOC)   { src = t_in; dstb = tinb; lrow = row - (BTOK + VOC); }
        else                           { src = t_w;  dstb = twb;  lrow = row - (2*BTOK + VOC); }
        const float4 v = *reinterpret_cast<const float4*>(src + (size_t)lrow * HDIM + c4 * 4);
        const int p = lrow >> 7, r = lrow & 127;
        const int c = c4 * 4, kt = c >> 5, cc = c & 31;
        const int e = (r * BK + cc) ^ ((r & 7) << 3);   // full-address XOR
        ushort4 h;
        h.x = f2b(v.x); h.y = f2b(v.y); h.z = f2b(v.z); h.w = f2b(v.w);
        *reinterpret_cast<ushort4*>(dstb + (size_t)(p * NKT + kt) * BLOB_E + e) = h;
    }
}

// ---------------------------------------------------------------------------
// Pass 2: dual bf16 GEMM + loss partials. Double-buffered LDS, counted
// vmcnt (T4): next K-step's global_load_lds stay in flight across the
// barrier; only the last step drains to 0.
// ---------------------------------------------------------------------------
__device__ __forceinline__ void gl_lds16(const unsigned short* g, unsigned short* l) {
    __builtin_amdgcn_global_load_lds(
        (__attribute__((address_space(1))) const void*)g,
        (__attribute__((address_space(3))) void*)l, 16, 0, 0);
}

__global__ __launch_bounds__(256, 2) void fused_gemm(
    const unsigned short* __restrict__ blob,
    const int* __restrict__ labels, float* __restrict__ rowacc)
{
    __shared__ unsigned short smem[2][4][BLOB_E];   // dbuf x {As,Bs,At,Bt}: 64 KB
    __shared__ int lbl[BM];
    const unsigned short* sinb = blob;
    const unsigned short* tinb = blob + INB_E;
    const unsigned short* swb  = blob + 2 * INB_E;
    const unsigned short* twb  = blob + 2 * INB_E + WB_E;

    const int tid = threadIdx.x;
    // XCD-bijective swizzle (4000 % 8 == 0), row-block fastest: the 16 blocks
    // sharing a weight slab run consecutively on one XCD's L2.
    const int orig = blockIdx.x;
    const int swz  = (orig & 7) * (NBLK / 8) + (orig >> 3);
    const int vb = swz >> 4, rb = swz & 15;
    const int n0 = vb * BN, row0 = rb * BM;
    if (tid < BM) lbl[tid] = labels[row0 + tid];

    f32x4 acc_s[4][4] = {};
    f32x4 acc_t[4][4] = {};
    const int lane = tid & 63, wave = tid >> 6;
    const int wm = (wave >> 1) * 64, wn = (wave & 1) * 64;
    const int lr = lane & 15, lg = lane >> 4;
    const int xorv = (lr & 7) << 3;     // full-address XOR value (bit5 = row-LSB flip)

    const unsigned short* g0 = sinb + (size_t)(rb * NKT) * BLOB_E;
    const unsigned short* g1 = swb  + (size_t)(vb * NKT) * BLOB_E;
    const unsigned short* g2 = tinb + (size_t)(rb * NKT) * BLOB_E;
    const unsigned short* g3 = twb  + (size_t)(vb * NKT) * BLOB_E;

#define STAGE(KT, B)                                                          \
    {                                                                         \
        const size_t kb = (size_t)(KT) * BLOB_E;                              \
        _Pragma("unroll")                                                     \
        for (int i = 0; i < 2; ++i) {                                         \
            const int off = wave * 1024 + i * 512 + lane * 8;                 \
            gl_lds16(g0 + kb + off, &smem[B][0][off]);                        \
            gl_lds16(g1 + kb + off, &smem[B][1][off]);                        \
            gl_lds16(g2 + kb + off, &smem[B][2][off]);                        \
            gl_lds16(g3 + kb + off, &smem[B][3][off]);                        \
        }                                                                     \
    }

#define COMPUTE(B)                                                            \
    {                                                                         \
        bf16x8 af[4], bfr[4];                                                 \
        _Pragma("unroll")                                                     \
        for (int mi = 0; mi < 4; ++mi)                                        \
            af[mi] = *reinterpret_cast<const bf16x8*>(                        \
                &smem[B][0][((wm + mi * 16 + lr) * BK + lg * 8) ^ xorv]);     \
        _Pragma("unroll")                                                     \
        for (int ni = 0; ni < 4; ++ni)                                        \
            bfr[ni] = *reinterpret_cast<const bf16x8*>(                       \
                &smem[B][1][((wn + ni * 16 + lr) * BK + lg * 8) ^ xorv]);     \
        _Pragma("unroll")                                                     \
        for (int mi = 0; mi < 4; ++mi)                                        \
            _Pragma("unroll")                                                 \
            for (int ni = 0; ni < 4; ++ni)                                    \
                acc_s[mi][ni] = __builtin_amdgcn_mfma_f32_16x16x32_bf16(      \
                    af[mi], bfr[ni], acc_s[mi][ni], 0, 0, 0);                 \
        _Pragma("unroll")                                                     \
        for (int mi = 0; mi < 4; ++mi)                                        \
            af[mi] = *reinterpret_cast<const bf16x8*>(                        \
                &smem[B][2][((wm + mi * 16 + lr) * BK + lg * 8) ^ xorv]);     \
        _Pragma("unroll")                                                     \
        for (int ni = 0; ni < 4; ++ni)                                        \
            bfr[ni] = *reinterpret_cast<const bf16x8*>(                       \
                &smem[B][3][((wn + ni * 16 + lr) * BK + lg * 8) ^ xorv]);     \
        _Pragma("unroll")                                                     \
        for (int mi = 0; mi < 4; ++mi)                                        \
            _Pragma("unroll")                                                 \
            for (int ni = 0; ni < 4; ++ni)                                    \
                acc_t[mi][ni] = __builtin_amdgcn_mfma_f32_16x16x32_bf16(      \
                    af[mi], bfr[ni], acc_t[mi][ni], 0, 0, 0);                 \
    }

// One K-step: issue next loads early; counted vmcnt keeps them in flight
// across the barrier (T4). Trailing barrier releases this buf for restaging.
#define STEP(KT, B)                                                           \
    {                                                                         \
        if ((KT) + 1 < NKT) {                                                 \
            STAGE((KT) + 1, (B) ^ 1);                                         \
            asm volatile("s_waitcnt vmcnt(8)" ::: "memory");                  \
        } else {                                                              \
            asm volatile("s_waitcnt vmcnt(0)" ::: "memory");                  \
        }                                                                     \
        __builtin_amdgcn_sched_barrier(0);                                    \
        __builtin_amdgcn_s_barrier();                                         \
        COMPUTE(B);                                                           \
        __builtin_amdgcn_s_barrier();                                         \
    }

    STAGE(0, 0);
#pragma unroll 2
    for (int kt = 0; kt < NKT; kt += 2) {
        STEP(kt, 0);
        STEP(kt + 1, 1);
    }

#undef STAGE
#undef COMPUTE
#undef STEP

    // Epilogue: per-row online partials. D layout: col=lane&15, row=(lane>>4)*4+reg.
#pragma unroll
    for (int mi = 0; mi < 4; ++mi) {
#pragma unroll
        for (int rg_ = 0; rg_ < 4; ++rg_) {
            const int rloc = wm + mi * 16 + lg * 4 + rg_;
            const int lab = lbl[rloc];
            float es = 0.f, dt = 0.f, ss = 0.f, tt = 0.f, sl = 0.f;
#pragma unroll
            for (int ni = 0; ni < 4; ++ni) {
                const float s = acc_s[mi][ni][rg_];
                const float t = acc_t[mi][ni][rg_];
                es += __expf(s);
                dt += s * t;
                ss += s * s;
                tt += t * t;
                if (n0 + wn + ni * 16 + lr == lab) sl += s;
            }
#pragma unroll
            for (int m = 1; m < 16; m <<= 1) {
                es += __shfl_xor(es, m, 64);
                dt += __shfl_xor(dt, m, 64);
                ss += __shfl_xor(ss, m, 64);
                tt += __shfl_xor(tt, m, 64);
                sl += __shfl_xor(sl, m, 64);
            }
            if (lr == 0) {
                float* ra = rowacc + (size_t)(row0 + rloc) * 5;
                atomicAdd(ra + 0, es);
                atomicAdd(ra + 1, dt);
                atomicAdd(ra + 2, ss);
                atomicAdd(ra + 3, tt);
                atomicAdd(ra + 4, sl);
            }
        }
    }
}

// ---------------------------------------------------------------------------
// Fallback (ws too small): R2's validated fused-conversion kernel.
// ---------------------------------------------------------------------------
#define BKF 32
#define NKTF (HDIM / BKF)
#define TILE_EF (BM * BKF)

__device__ __forceinline__ int swz_e32(int r, int c) {
    return (r * BKF + c) ^ ((r & 7) << 3);
}

__global__ __launch_bounds__(256, 2) void fused_fwd_fb(
    const float* __restrict__ s_in, const float* __restrict__ s_w,
    const float* __restrict__ t_in, const float* __restrict__ t_w,
    const int* __restrict__ labels, float* __restrict__ rowacc)
{
    __shared__ unsigned short smem[2][4][TILE_EF];
    __shared__ int lbl[BM];
    const int tid = threadIdx.x;
    const int orig = blockIdx.x;
    const int swz  = (orig & 7) * (NBLK / 8) + (orig >> 3);
    const int vb = swz >> 4, rb = swz & 15;
    const int n0 = vb * BN, row0 = rb * BM;
    if (tid < BM) lbl[tid] = labels[row0 + tid];
    const int rr = tid >> 3, c8 = tid & 7;
    const float* srcp[4];
    srcp[0] = s_in + (size_t)(row0 + rr) * HDIM + c8 * 4;
    srcp[1] = s_w  + (size_t)(n0   + rr) * HDIM + c8 * 4;
    srcp[2] = t_in + (size_t)(row0 + rr) * HDIM + c8 * 4;
    srcp[3] = t_w  + (size_t)(n0   + rr) * HDIM + c8 * 4;
    f32x4 acc_s[4][4] = {}, acc_t[4][4] = {};
    const int lane = tid & 63, wave = tid >> 6;
    const int wm = (wave >> 1) * 64, wn = (wave & 1) * 64;
    const int lr = lane & 15, lg = lane >> 4;
    const int ec = lg * 8;
    float4 rg[4][4];

#define LOADS_FB(KT)                                                          \
    { const int k0 = (KT) * BKF;                                              \
      _Pragma("unroll") for (int t = 0; t < 4; ++t)                           \
      _Pragma("unroll") for (int it = 0; it < 4; ++it)                        \
          rg[t][it] = *reinterpret_cast<const float4*>(srcp[t] + (size_t)it * 32 * HDIM + k0); }
#define CVT_WRITE_FB(B)                                                       \
    { _Pragma("unroll") for (int t = 0; t < 4; ++t)                           \
      _Pragma("unroll") for (int it = 0; it < 4; ++it) {                      \
          const int r = rr + it * 32;                                         \
          ushort4 h;                                                          \
          h.x = f2b(rg[t][it].x); h.y = f2b(rg[t][it].y);                     \
          h.z = f2b(rg[t][it].z); h.w = f2b(rg[t][it].w);                     \
          *reinterpret_cast<ushort4*>(&smem[B][t][swz_e32(r, c8 * 4)]) = h; } }
#define COMPUTE_FB(B)                                                         \
    { const unsigned short* As = smem[B][0]; const unsigned short* Bs = smem[B][1]; \
      const unsigned short* At = smem[B][2]; const unsigned short* Bt = smem[B][3]; \
      bf16x8 af[4], bfr[4];                                                   \
      _Pragma("unroll") for (int mi = 0; mi < 4; ++mi)                        \
          af[mi] = *reinterpret_cast<const bf16x8*>(As + swz_e32(wm + mi * 16 + lr, ec)); \
      _Pragma("unroll") for (int ni = 0; ni < 4; ++ni)                        \
          bfr[ni] = *reinterpret_cast<const bf16x8*>(Bs + swz_e32(wn + ni * 16 + lr, ec)); \
      _Pragma("unroll") for (int mi = 0; mi < 4; ++mi)                        \
      _Pragma("unroll") for (int ni = 0; ni < 4; ++ni)                        \
          acc_s[mi][ni] = __builtin_amdgcn_mfma_f32_16x16x32_bf16(af[mi], bfr[ni], acc_s[mi][ni], 0, 0, 0); \
      _Pragma("unroll") for (int mi = 0; mi < 4; ++mi)                        \
          af[mi] = *reinterpret_cast<const bf16x8*>(At + swz_e32(wm + mi * 16 + lr, ec)); \
      _Pragma("unroll") for (int ni = 0; ni < 4; ++ni)                        \
          bfr[ni] = *reinterpret_cast<const bf16x8*>(Bt + swz_e32(wn + ni * 16 + lr, ec)); \
      _Pragma("unroll") for (int mi = 0; mi < 4; ++mi)                        \
      _Pragma("unroll") for (int ni = 0; ni < 4; ++ni)                        \
          acc_t[mi][ni] = __builtin_amdgcn_mfma_f32_16x16x32_bf16(af[mi], bfr[ni], acc_t[mi][ni], 0, 0, 0); }

    LOADS_FB(0); CVT_WRITE_FB(0); __syncthreads();
    int cur = 0;
#pragma unroll 2
    for (int kt = 0; kt < NKTF; ++kt) {
        if (kt + 1 < NKTF) LOADS_FB(kt + 1);
        COMPUTE_FB(cur);
        if (kt + 1 < NKTF) CVT_WRITE_FB(cur ^ 1);
        __syncthreads();
        cur ^= 1;
    }
#undef LOADS_FB
#undef CVT_WRITE_FB
#undef COMPUTE_FB
#pragma unroll
    for (int mi = 0; mi < 4; ++mi) {
#pragma unroll
        for (int rg_ = 0; rg_ < 4; ++rg_) {
            const int rloc = wm + mi * 16 + lg * 4 + rg_;
            const int lab = lbl[rloc];
            float es = 0.f, dt = 0.f, ss = 0.f, tt = 0.f, sl = 0.f;
#pragma unroll
            for (int ni = 0; ni < 4; ++ni) {
                const float s = acc_s[mi][ni][rg_];
                const float t = acc_t[mi][ni][rg_];
                es += __expf(s); dt += s * t; ss += s * s; tt += t * t;
                if (n0 + wn + ni * 16 + lr == lab) sl += s;
            }
#pragma unroll
            for (int m = 1; m < 16; m <<= 1) {
                es += __shfl_xor(es, m, 64); dt += __shfl_xor(dt, m, 64);
                ss += __shfl_xor(ss, m, 64); tt += __shfl_xor(tt, m, 64);
                sl += __shfl_xor(sl, m, 64);
            }
            if (lr == 0) {
                float* ra = rowacc + (size_t)(row0 + rloc) * 5;
                atomicAdd(ra + 0, es); atomicAdd(ra + 1, dt); atomicAdd(ra + 2, ss);
                atomicAdd(ra + 3, tt); atomicAdd(ra + 4, sl);
            }
        }
    }
}

__global__ __launch_bounds__(256) void finalize(const float* __restrict__ rowacc,
                                                const int* __restrict__ labels,
                                                float* __restrict__ out)
{
    const int tid = threadIdx.x;
    float hard = 0.f, soft = 0.f;
    for (int r = tid; r < BTOK; r += 256) {
        const float* ra = rowacc + (size_t)r * 5;
        const float es = ra[0], dt = ra[1], ss = ra[2], tt = ra[3], sl = ra[4];
        if (labels[r] != -100) hard += logf(es) - sl;
        const float ns = fmaxf(sqrtf(ss), 1e-12f);
        const float nt = fmaxf(sqrtf(tt), 1e-12f);
        soft += 1.f - dt / (ns * nt);
    }
#pragma unroll
    for (int m = 1; m < 64; m <<= 1) {
        hard += __shfl_xor(hard, m, 64);
        soft += __shfl_xor(soft, m, 64);
    }
    __shared__ float sh[2][4];
    const int w = tid >> 6;
    if ((tid & 63) == 0) { sh[0][w] = hard; sh[1][w] = soft; }
    __syncthreads();
    if (tid == 0) {
        const float h = sh[0][0] + sh[0][1] + sh[0][2] + sh[0][3];
        const float s = sh[1][0] + sh[1][1] + sh[1][2] + sh[1][3];
        out[0] = 0.5f * (h / (float)BTOK) + 0.5f * (0.5f * s / (float)BTOK);
    }
}

extern "C" void kernel_launch(void* const* d_in, const int* in_sizes, int n_in,
                              void* d_out, int out_size, void* d_ws, size_t ws_size,
                              hipStream_t stream)
{
    const float* s_in   = (const float*)d_in[0];
    const float* s_w    = (const float*)d_in[1];
    const float* t_in   = (const float*)d_in[2];
    const float* t_w    = (const float*)d_in[3];
    const int*   labels = (const int*)d_in[4];
    float* rowacc = (float*)d_ws;

    hipMemsetAsync(rowacc, 0, (size_t)BTOK * 5 * sizeof(float), stream);

    if (ws_size >= WS_NEED) {
        unsigned short* blob = (unsigned short*)((char*)d_ws + WS_BLOB_OFF);
        convert_pack<<<2048, 256, 0, stream>>>(s_in, s_w, t_in, t_w, blob);
        fused_gemm<<<NBLK, 256, 0, stream>>>(blob, labels, rowacc);
    } else {
        fused_fwd_fb<<<NBLK, 256, 0, stream>>>(s_in, s_w, t_in, t_w, labels, rowacc);
    }
    finalize<<<1, 256, 0, stream>>>(rowacc, labels, (float*)d_out);
}

// Round 6
// 301.029 us; speedup vs baseline: 1.8587x; 1.8587x over previous
//
#include <hip/hip_runtime.h>
#include <stdint.h>

#define BTOK 2048
#define HDIM 512
#define VOC  32000
#define BM 128
#define BN 128
#define BK 32
#define NKT (HDIM / BK)          // 16 K-steps
#define BLOB_E (BM * BK)         // 4096 ushorts = 8 KB per (panel, kt) blob
#define NVB (VOC / BN)           // 250
#define NRB (BTOK / BM)          // 16
#define NBLK (NVB * NRB)         // 4000 (atomic fallback grid)
#define VBG 2                    // vocab blocks per strip
#define NVBG (NVB / VBG)         // 125
#define NSTRIP (NVBG * NRB)      // 2000 strip blocks
#define NSLOT (NVBG * 2)         // 250 partial slots (vbg x wave-half)

// ws layout (strip tier):
//   [0, 256)        blocksums (64 f32, finalize stage 1 -> 2)
//   [0, 40960)      rowacc (atomic fallback tier only)
//   [65536, ..)     bf16 blobs: s_in | t_in | s_w | t_w
//   [PART_OFF, ..)  partials[5][NSLOT][BTOK] f32
#define WS_BLOB_OFF 65536
#define INB_E (BTOK * HDIM)      // 1,048,576 ushorts
#define WB_E  (VOC * HDIM)       // 16,384,000 ushorts
#define BLOB_BYTES ((size_t)(2 * INB_E + 2 * WB_E) * 2)
#define WS_NEED1 (WS_BLOB_OFF + BLOB_BYTES)            // 69,795,840
#define PART_OFF WS_NEED1
#define PART_BYTES ((size_t)5 * NSLOT * BTOK * 4)      // 10,240,000
#define WS_NEED2 (PART_OFF + PART_BYTES)               // 80,035,840

typedef __attribute__((ext_vector_type(8))) short bf16x8;
typedef __attribute__((ext_vector_type(4))) float f32x4;

__device__ __forceinline__ unsigned short f2b(float f) {
    union { float f; uint32_t u; } x; x.f = f;
    uint32_t u = x.u;
    u += 0x7fffu + ((u >> 16) & 1u);   // RNE
    return (unsigned short)(u >> 16);
}

// ---------------------------------------------------------------------------
// Pass 1: f32 -> bf16 blobs with FULL-ADDRESS XOR swizzle pre-applied:
//   e = (r*32 + cc) ^ ((r&7)<<3)   (bit5 of X flips the row LSB - bijective)
// GEMM stages blobs linearly via global_load_lds and reads with the same
// full-address XOR (rule #21: same involution both sides).
// ---------------------------------------------------------------------------
__global__ __launch_bounds__(256) void convert_pack(
    const float* __restrict__ s_in, const float* __restrict__ s_w,
    const float* __restrict__ t_in, const float* __restrict__ t_w,
    unsigned short* __restrict__ blob)
{
    unsigned short* sinb = blob;
    unsigned short* tinb = blob + INB_E;
    unsigned short* swb  = blob + 2 * INB_E;
    unsigned short* twb  = blob + 2 * INB_E + WB_E;
    const int total4 = (2 * BTOK + 2 * VOC) * (HDIM / 4);
    for (int f = blockIdx.x * 256 + threadIdx.x; f < total4; f += gridDim.x * 256) {
        const int row = f >> 7;            // 128 float4 per source row
        const int c4  = f & 127;
        const float* src; unsigned short* dstb; int lrow;
        if (row < BTOK)                { src = s_in; dstb = sinb; lrow = row; }
        else if (row < BTOK + VOC)     { src = s_w;  dstb = swb;  lrow = row - BTOK; }
        else if (row < 2*BTOK + VOC)   { src = t_in; dstb = tinb; lrow = row - (BTOK + VOC); }
        else                           { src = t_w;  dstb = twb;  lrow = row - (2*BTOK + VOC); }
        const float4 v = *reinterpret_cast<const float4*>(src + (size_t)lrow * HDIM + c4 * 4);
        const int p = lrow >> 7, r = lrow & 127;
        const int c = c4 * 4, kt = c >> 5, cc = c & 31;
        const int e = (r * BK + cc) ^ ((r & 7) << 3);   // full-address XOR
        ushort4 h;
        h.x = f2b(v.x); h.y = f2b(v.y); h.z = f2b(v.z); h.w = f2b(v.w);
        *reinterpret_cast<ushort4*>(dstb + (size_t)(p * NKT + kt) * BLOB_E + e) = h;
    }
}

__device__ __forceinline__ void gl_lds16(const unsigned short* g, unsigned short* l) {
    __builtin_amdgcn_global_load_lds(
        (__attribute__((address_space(1))) const void*)g,
        (__attribute__((address_space(3))) void*)l, 16, 0, 0);
}

// Shared macros for the K-loop (used by both GEMM kernels).
#define STAGE(KT, B)                                                          \
    {                                                                         \
        const size_t kb = (size_t)(KT) * BLOB_E;                              \
        _Pragma("unroll")                                                     \
        for (int i = 0; i < 2; ++i) {                                         \
            const int off = wave * 1024 + i * 512 + lane * 8;                 \
            gl_lds16(g0 + kb + off, &smem[B][0][off]);                        \
            gl_lds16(g1 + kb + off, &smem[B][1][off]);                        \
            gl_lds16(g2 + kb + off, &smem[B][2][off]);                        \
            gl_lds16(g3 + kb + off, &smem[B][3][off]);                        \
        }                                                                     \
    }

#define COMPUTE(B)                                                            \
    {                                                                         \
        bf16x8 af[4], bfr[4];                                                 \
        _Pragma("unroll")                                                     \
        for (int mi = 0; mi < 4; ++mi)                                        \
            af[mi] = *reinterpret_cast<const bf16x8*>(                        \
                &smem[B][0][((wm + mi * 16 + lr) * BK + lg * 8) ^ xorv]);     \
        _Pragma("unroll")                                                     \
        for (int ni = 0; ni < 4; ++ni)                                        \
            bfr[ni] = *reinterpret_cast<const bf16x8*>(                       \
                &smem[B][1][((wn + ni * 16 + lr) * BK + lg * 8) ^ xorv]);     \
        _Pragma("unroll")                                                     \
        for (int mi = 0; mi < 4; ++mi)                                        \
            _Pragma("unroll")                                                 \
            for (int ni = 0; ni < 4; ++ni)                                    \
                acc_s[mi][ni] = __builtin_amdgcn_mfma_f32_16x16x32_bf16(      \
                    af[mi], bfr[ni], acc_s[mi][ni], 0, 0, 0);                 \
        _Pragma("unroll")                                                     \
        for (int mi = 0; mi < 4; ++mi)                                        \
            af[mi] = *reinterpret_cast<const bf16x8*>(                        \
                &smem[B][2][((wm + mi * 16 + lr) * BK + lg * 8) ^ xorv]);     \
        _Pragma("unroll")                                                     \
        for (int ni = 0; ni < 4; ++ni)                                        \
            bfr[ni] = *reinterpret_cast<const bf16x8*>(                       \
                &smem[B][3][((wn + ni * 16 + lr) * BK + lg * 8) ^ xorv]);     \
        _Pragma("unroll")                                                     \
        for (int mi = 0; mi < 4; ++mi)                                        \
            _Pragma("unroll")                                                 \
            for (int ni = 0; ni < 4; ++ni)                                    \
                acc_t[mi][ni] = __builtin_amdgcn_mfma_f32_16x16x32_bf16(      \
                    af[mi], bfr[ni], acc_t[mi][ni], 0, 0, 0);                 \
    }

// Counted vmcnt (T4): next K-step's loads stay in flight across the barrier.
#define STEP(KT, B)                                                           \
    {                                                                         \
        if ((KT) + 1 < NKT) {                                                 \
            STAGE((KT) + 1, (B) ^ 1);                                         \
            asm volatile("s_waitcnt vmcnt(8)" ::: "memory");                  \
        } else {                                                              \
            asm volatile("s_waitcnt vmcnt(0)" ::: "memory");                  \
        }                                                                     \
        __builtin_amdgcn_sched_barrier(0);                                    \
        __builtin_amdgcn_s_barrier();                                         \
        COMPUTE(B);                                                           \
        __builtin_amdgcn_s_barrier();                                         \
    }

// ---------------------------------------------------------------------------
// Strip GEMM: (row-block, 2 vocab-blocks) per block; loss partials accumulate
// in REGISTERS across the strip; ONE non-atomic partials write at the end.
// Zero global atomics (R5 diagnosis: 5.1M rowacc atomics = 160 MB HBM RMW
// + ~550us serialization floor).
// ---------------------------------------------------------------------------
__global__ __launch_bounds__(256, 2) void fused_gemm_strip(
    const unsigned short* __restrict__ blob,
    const int* __restrict__ labels, float* __restrict__ partials)
{
    __shared__ unsigned short smem[2][4][BLOB_E];   // dbuf x {As,Bs,At,Bt}: 64 KB
    __shared__ int lbl[BM];
    const unsigned short* sinb = blob;
    const unsigned short* tinb = blob + INB_E;
    const unsigned short* swb  = blob + 2 * INB_E;
    const unsigned short* twb  = blob + 2 * INB_E + WB_E;

    const int tid = threadIdx.x;
    // XCD-bijective swizzle (2000 % 8 == 0), row-block fastest.
    const int orig = blockIdx.x;
    const int swz  = (orig & 7) * (NSTRIP / 8) + (orig >> 3);
    const int vbg = swz >> 4, rb = swz & 15;
    const int row0 = rb * BM;
    if (tid < BM) lbl[tid] = labels[row0 + tid];

    const int lane = tid & 63, wave = tid >> 6;
    const int wm = (wave >> 1) * 64, wn = (wave & 1) * 64;
    const int lr = lane & 15, lg = lane >> 4;
    const int xorv = (lr & 7) << 3;

    const unsigned short* g0 = sinb + (size_t)(rb * NKT) * BLOB_E;
    const unsigned short* g2 = tinb + (size_t)(rb * NKT) * BLOB_E;

    // per-lane loss partials, accumulated across the strip (80 VGPRs)
    float pes[4][4] = {}, pdt[4][4] = {}, pss[4][4] = {}, ptt[4][4] = {}, psl[4][4] = {};

    for (int g = 0; g < VBG; ++g) {
        const int vb = vbg * VBG + g;
        const int n0 = vb * BN;
        const unsigned short* g1 = swb + (size_t)(vb * NKT) * BLOB_E;
        const unsigned short* g3 = twb + (size_t)(vb * NKT) * BLOB_E;

        f32x4 acc_s[4][4] = {};
        f32x4 acc_t[4][4] = {};

        STAGE(0, 0);
#pragma unroll 2
        for (int kt = 0; kt < NKT; kt += 2) {
            STEP(kt, 0);
            STEP(kt + 1, 1);
        }

        // accumulate per-lane partials (D layout: col=lane&15, row=(lane>>4)*4+reg)
#pragma unroll
        for (int mi = 0; mi < 4; ++mi) {
#pragma unroll
            for (int rg_ = 0; rg_ < 4; ++rg_) {
                const int rloc = wm + mi * 16 + lg * 4 + rg_;
                const int lab = lbl[rloc];
#pragma unroll
                for (int ni = 0; ni < 4; ++ni) {
                    const float s = acc_s[mi][ni][rg_];
                    const float t = acc_t[mi][ni][rg_];
                    pes[mi][rg_] += __expf(s);
                    pdt[mi][rg_] += s * t;
                    pss[mi][rg_] += s * s;
                    ptt[mi][rg_] += t * t;
                    if (n0 + wn + ni * 16 + lr == lab) psl[mi][rg_] += s;
                }
            }
        }
    }

    // one shuffle-reduce + one non-atomic write per (mi,rg_)
    const int slot = vbg * 2 + (wave & 1);
#pragma unroll
    for (int mi = 0; mi < 4; ++mi) {
#pragma unroll
        for (int rg_ = 0; rg_ < 4; ++rg_) {
            float es = pes[mi][rg_], dt = pdt[mi][rg_], ss = pss[mi][rg_];
            float tt = ptt[mi][rg_], sl = psl[mi][rg_];
#pragma unroll
            for (int m = 1; m < 16; m <<= 1) {
                es += __shfl_xor(es, m, 64);
                dt += __shfl_xor(dt, m, 64);
                ss += __shfl_xor(ss, m, 64);
                tt += __shfl_xor(tt, m, 64);
                sl += __shfl_xor(sl, m, 64);
            }
            if (lr == 0) {
                const int row = row0 + wm + mi * 16 + lg * 4 + rg_;
                partials[(size_t)(0 * NSLOT + slot) * BTOK + row] = es;
                partials[(size_t)(1 * NSLOT + slot) * BTOK + row] = dt;
                partials[(size_t)(2 * NSLOT + slot) * BTOK + row] = ss;
                partials[(size_t)(3 * NSLOT + slot) * BTOK + row] = tt;
                partials[(size_t)(4 * NSLOT + slot) * BTOK + row] = sl;
            }
        }
    }
}

// ---------------------------------------------------------------------------
// Middle-tier fallback: R5's validated atomic-rowacc GEMM (ws too small for
// partials but fits blobs).
// ---------------------------------------------------------------------------
__global__ __launch_bounds__(256, 2) void fused_gemm(
    const unsigned short* __restrict__ blob,
    const int* __restrict__ labels, float* __restrict__ rowacc)
{
    __shared__ unsigned short smem[2][4][BLOB_E];
    __shared__ int lbl[BM];
    const unsigned short* sinb = blob;
    const unsigned short* tinb = blob + INB_E;
    const unsigned short* swb  = blob + 2 * INB_E;
    const unsigned short* twb  = blob + 2 * INB_E + WB_E;

    const int tid = threadIdx.x;
    const int orig = blockIdx.x;
    const int swz  = (orig & 7) * (NBLK / 8) + (orig >> 3);
    const int vb = swz >> 4, rb = swz & 15;
    const int n0 = vb * BN, row0 = rb * BM;
    if (tid < BM) lbl[tid] = labels[row0 + tid];

    f32x4 acc_s[4][4] = {};
    f32x4 acc_t[4][4] = {};
    const int lane = tid & 63, wave = tid >> 6;
    const int wm = (wave >> 1) * 64, wn = (wave & 1) * 64;
    const int lr = lane & 15, lg = lane >> 4;
    const int xorv = (lr & 7) << 3;

    const unsigned short* g0 = sinb + (size_t)(rb * NKT) * BLOB_E;
    const unsigned short* g1 = swb  + (size_t)(vb * NKT) * BLOB_E;
    const unsigned short* g2 = tinb + (size_t)(rb * NKT) * BLOB_E;
    const unsigned short* g3 = twb  + (size_t)(vb * NKT) * BLOB_E;

    STAGE(0, 0);
#pragma unroll 2
    for (int kt = 0; kt < NKT; kt += 2) {
        STEP(kt, 0);
        STEP(kt + 1, 1);
    }

#pragma unroll
    for (int mi = 0; mi < 4; ++mi) {
#pragma unroll
        for (int rg_ = 0; rg_ < 4; ++rg_) {
            const int rloc = wm + mi * 16 + lg * 4 + rg_;
            const int lab = lbl[rloc];
            float es = 0.f, dt = 0.f, ss = 0.f, tt = 0.f, sl = 0.f;
#pragma unroll
            for (int ni = 0; ni < 4; ++ni) {
                const float s = acc_s[mi][ni][rg_];
                const float t = acc_t[mi][ni][rg_];
                es += __expf(s);
                dt += s * t;
                ss += s * s;
                tt += t * t;
                if (n0 + wn + ni * 16 + lr == lab) sl += s;
            }
#pragma unroll
            for (int m = 1; m < 16; m <<= 1) {
                es += __shfl_xor(es, m, 64);
                dt += __shfl_xor(dt, m, 64);
                ss += __shfl_xor(ss, m, 64);
                tt += __shfl_xor(tt, m, 64);
                sl += __shfl_xor(sl, m, 64);
            }
            if (lr == 0) {
                float* ra = rowacc + (size_t)(row0 + rloc) * 5;
                atomicAdd(ra + 0, es);
                atomicAdd(ra + 1, dt);
                atomicAdd(ra + 2, ss);
                atomicAdd(ra + 3, tt);
                atomicAdd(ra + 4, sl);
            }
        }
    }
}

// ---------------------------------------------------------------------------
// finalize stage 1 (strip tier): 32 blocks x 64 rows; reduce 250 slots.
// Coalesced: for fixed (j,slot), 64 lanes read 64 consecutive rows.
// ---------------------------------------------------------------------------
__global__ __launch_bounds__(256) void finalize_s1(
    const float* __restrict__ partials, const int* __restrict__ labels,
    float* __restrict__ blocksums)
{
    __shared__ float fsum[4][64][5];
    const int t = threadIdx.x, b = blockIdx.x;
    const int rl = t & 63, w = t >> 6;
    const int row = b * 64 + rl;
    float a0 = 0.f, a1 = 0.f, a2 = 0.f, a3 = 0.f, a4 = 0.f;
    for (int slot = w; slot < NSLOT; slot += 4) {
        const size_t base = (size_t)slot * BTOK + row;
        a0 += partials[(size_t)0 * NSLOT * BTOK + base];
        a1 += partials[(size_t)1 * NSLOT * BTOK + base];
        a2 += partials[(size_t)2 * NSLOT * BTOK + base];
        a3 += partials[(size_t)3 * NSLOT * BTOK + base];
        a4 += partials[(size_t)4 * NSLOT * BTOK + base];
    }
    fsum[w][rl][0] = a0; fsum[w][rl][1] = a1; fsum[w][rl][2] = a2;
    fsum[w][rl][3] = a3; fsum[w][rl][4] = a4;
    __syncthreads();
    if (t < 64) {
        const float es = fsum[0][t][0] + fsum[1][t][0] + fsum[2][t][0] + fsum[3][t][0];
        const float dt = fsum[0][t][1] + fsum[1][t][1] + fsum[2][t][1] + fsum[3][t][1];
        const float ss = fsum[0][t][2] + fsum[1][t][2] + fsum[2][t][2] + fsum[3][t][2];
        const float tt = fsum[0][t][3] + fsum[1][t][3] + fsum[2][t][3] + fsum[3][t][3];
        const float sl = fsum[0][t][4] + fsum[1][t][4] + fsum[2][t][4] + fsum[3][t][4];
        float hard = 0.f, soft;
        if (labels[row] != -100) hard = logf(es) - sl;
        const float ns = fmaxf(sqrtf(ss), 1e-12f);
        const float nt = fmaxf(sqrtf(tt), 1e-12f);
        soft = 1.f - dt / (ns * nt);
#pragma unroll
        for (int m = 1; m < 64; m <<= 1) {
            hard += __shfl_xor(hard, m, 64);
            soft += __shfl_xor(soft, m, 64);
        }
        if (t == 0) {
            blocksums[b * 2 + 0] = hard;
            blocksums[b * 2 + 1] = soft;
        }
    }
}

__global__ void finalize_s2(const float* __restrict__ blocksums,
                            float* __restrict__ out)
{
    const int t = threadIdx.x;   // 64 threads
    float hard = (t < 32) ? blocksums[t * 2 + 0] : 0.f;
    float soft = (t < 32) ? blocksums[t * 2 + 1] : 0.f;
#pragma unroll
    for (int m = 1; m < 64; m <<= 1) {
        hard += __shfl_xor(hard, m, 64);
        soft += __shfl_xor(soft, m, 64);
    }
    if (t == 0)
        out[0] = 0.5f * (hard / (float)BTOK) + 0.25f * (soft / (float)BTOK);
}

// ---------------------------------------------------------------------------
// Low-tier fallback: R2's validated fused-conversion kernel + atomic rowacc.
// ---------------------------------------------------------------------------
#define BKF 32
#define NKTF (HDIM / BKF)
#define TILE_EF (BM * BKF)

__device__ __forceinline__ int swz_e32(int r, int c) {
    return (r * BKF + c) ^ ((r & 7) << 3);
}

__global__ __launch_bounds__(256, 2) void fused_fwd_fb(
    const float* __restrict__ s_in, const float* __restrict__ s_w,
    const float* __restrict__ t_in, const float* __restrict__ t_w,
    const int* __restrict__ labels, float* __restrict__ rowacc)
{
    __shared__ unsigned short smem[2][4][TILE_EF];
    __shared__ int lbl[BM];
    const int tid = threadIdx.x;
    const int orig = blockIdx.x;
    const int swz  = (orig & 7) * (NBLK / 8) + (orig >> 3);
    const int vb = swz >> 4, rb = swz & 15;
    const int n0 = vb * BN, row0 = rb * BM;
    if (tid < BM) lbl[tid] = labels[row0 + tid];
    const int rr = tid >> 3, c8 = tid & 7;
    const float* srcp[4];
    srcp[0] = s_in + (size_t)(row0 + rr) * HDIM + c8 * 4;
    srcp[1] = s_w  + (size_t)(n0   + rr) * HDIM + c8 * 4;
    srcp[2] = t_in + (size_t)(row0 + rr) * HDIM + c8 * 4;
    srcp[3] = t_w  + (size_t)(n0   + rr) * HDIM + c8 * 4;
    f32x4 acc_s[4][4] = {}, acc_t[4][4] = {};
    const int lane = tid & 63, wave = tid >> 6;
    const int wm = (wave >> 1) * 64, wn = (wave & 1) * 64;
    const int lr = lane & 15, lg = lane >> 4;
    const int ec = lg * 8;
    float4 rg[4][4];

#define LOADS_FB(KT)                                                          \
    { const int k0 = (KT) * BKF;                                              \
      _Pragma("unroll") for (int t = 0; t < 4; ++t)                           \
      _Pragma("unroll") for (int it = 0; it < 4; ++it)                        \
          rg[t][it] = *reinterpret_cast<const float4*>(srcp[t] + (size_t)it * 32 * HDIM + k0); }
#define CVT_WRITE_FB(B)                                                       \
    { _Pragma("unroll") for (int t = 0; t < 4; ++t)                           \
      _Pragma("unroll") for (int it = 0; it < 4; ++it) {                      \
          const int r = rr + it * 32;                                         \
          ushort4 h;                                                          \
          h.x = f2b(rg[t][it].x); h.y = f2b(rg[t][it].y);                     \
          h.z = f2b(rg[t][it].z); h.w = f2b(rg[t][it].w);                     \
          *reinterpret_cast<ushort4*>(&smem[B][t][swz_e32(r, c8 * 4)]) = h; } }
#define COMPUTE_FB(B)                                                         \
    { const unsigned short* As = smem[B][0]; const unsigned short* Bs = smem[B][1]; \
      const unsigned short* At = smem[B][2]; const unsigned short* Bt = smem[B][3]; \
      bf16x8 af[4], bfr[4];                                                   \
      _Pragma("unroll") for (int mi = 0; mi < 4; ++mi)                        \
          af[mi] = *reinterpret_cast<const bf16x8*>(As + swz_e32(wm + mi * 16 + lr, ec)); \
      _Pragma("unroll") for (int ni = 0; ni < 4; ++ni)                        \
          bfr[ni] = *reinterpret_cast<const bf16x8*>(Bs + swz_e32(wn + ni * 16 + lr, ec)); \
      _Pragma("unroll") for (int mi = 0; mi < 4; ++mi)                        \
      _Pragma("unroll") for (int ni = 0; ni < 4; ++ni)                        \
          acc_s[mi][ni] = __builtin_amdgcn_mfma_f32_16x16x32_bf16(af[mi], bfr[ni], acc_s[mi][ni], 0, 0, 0); \
      _Pragma("unroll") for (int mi = 0; mi < 4; ++mi)                        \
          af[mi] = *reinterpret_cast<const bf16x8*>(At + swz_e32(wm + mi * 16 + lr, ec)); \
      _Pragma("unroll") for (int ni = 0; ni < 4; ++ni)                        \
          bfr[ni] = *reinterpret_cast<const bf16x8*>(Bt + swz_e32(wn + ni * 16 + lr, ec)); \
      _Pragma("unroll") for (int mi = 0; mi < 4; ++mi)                        \
      _Pragma("unroll") for (int ni = 0; ni < 4; ++ni)                        \
          acc_t[mi][ni] = __builtin_amdgcn_mfma_f32_16x16x32_bf16(af[mi], bfr[ni], acc_t[mi][ni], 0, 0, 0); }

    LOADS_FB(0); CVT_WRITE_FB(0); __syncthreads();
    int cur = 0;
#pragma unroll 2
    for (int kt = 0; kt < NKTF; ++kt) {
        if (kt + 1 < NKTF) LOADS_FB(kt + 1);
        COMPUTE_FB(cur);
        if (kt + 1 < NKTF) CVT_WRITE_FB(cur ^ 1);
        __syncthreads();
        cur ^= 1;
    }
#undef LOADS_FB
#undef CVT_WRITE_FB
#undef COMPUTE_FB
#pragma unroll
    for (int mi = 0; mi < 4; ++mi) {
#pragma unroll
        for (int rg_ = 0; rg_ < 4; ++rg_) {
            const int rloc = wm + mi * 16 + lg * 4 + rg_;
            const int lab = lbl[rloc];
            float es = 0.f, dt = 0.f, ss = 0.f, tt = 0.f, sl = 0.f;
#pragma unroll
            for (int ni = 0; ni < 4; ++ni) {
                const float s = acc_s[mi][ni][rg_];
                const float t = acc_t[mi][ni][rg_];
                es += __expf(s); dt += s * t; ss += s * s; tt += t * t;
                if (n0 + wn + ni * 16 + lr == lab) sl += s;
            }
#pragma unroll
            for (int m = 1; m < 16; m <<= 1) {
                es += __shfl_xor(es, m, 64); dt += __shfl_xor(dt, m, 64);
                ss += __shfl_xor(ss, m, 64); tt += __shfl_xor(tt, m, 64);
                sl += __shfl_xor(sl, m, 64);
            }
            if (lr == 0) {
                float* ra = rowacc + (size_t)(row0 + rloc) * 5;
                atomicAdd(ra + 0, es); atomicAdd(ra + 1, dt); atomicAdd(ra + 2, ss);
                atomicAdd(ra + 3, tt); atomicAdd(ra + 4, sl);
            }
        }
    }
}

__global__ __launch_bounds__(256) void finalize(const float* __restrict__ rowacc,
                                                const int* __restrict__ labels,
                                                float* __restrict__ out)
{
    const int tid = threadIdx.x;
    float hard = 0.f, soft = 0.f;
    for (int r = tid; r < BTOK; r += 256) {
        const float* ra = rowacc + (size_t)r * 5;
        const float es = ra[0], dt = ra[1], ss = ra[2], tt = ra[3], sl = ra[4];
        if (labels[r] != -100) hard += logf(es) - sl;
        const float ns = fmaxf(sqrtf(ss), 1e-12f);
        const float nt = fmaxf(sqrtf(tt), 1e-12f);
        soft += 1.f - dt / (ns * nt);
    }
#pragma unroll
    for (int m = 1; m < 64; m <<= 1) {
        hard += __shfl_xor(hard, m, 64);
        soft += __shfl_xor(soft, m, 64);
    }
    __shared__ float sh[2][4];
    const int w = tid >> 6;
    if ((tid & 63) == 0) { sh[0][w] = hard; sh[1][w] = soft; }
    __syncthreads();
    if (tid == 0) {
        const float h = sh[0][0] + sh[0][1] + sh[0][2] + sh[0][3];
        const float s = sh[1][0] + sh[1][1] + sh[1][2] + sh[1][3];
        out[0] = 0.5f * (h / (float)BTOK) + 0.5f * (0.5f * s / (float)BTOK);
    }
}

extern "C" void kernel_launch(void* const* d_in, const int* in_sizes, int n_in,
                              void* d_out, int out_size, void* d_ws, size_t ws_size,
                              hipStream_t stream)
{
    const float* s_in   = (const float*)d_in[0];
    const float* s_w    = (const float*)d_in[1];
    const float* t_in   = (const float*)d_in[2];
    const float* t_w    = (const float*)d_in[3];
    const int*   labels = (const int*)d_in[4];

    if (ws_size >= WS_NEED2) {
        unsigned short* blob = (unsigned short*)((char*)d_ws + WS_BLOB_OFF);
        float* partials  = (float*)((char*)d_ws + PART_OFF);
        float* blocksums = (float*)d_ws;
        convert_pack<<<2048, 256, 0, stream>>>(s_in, s_w, t_in, t_w, blob);
        fused_gemm_strip<<<NSTRIP, 256, 0, stream>>>(blob, labels, partials);
        finalize_s1<<<BTOK / 64, 256, 0, stream>>>(partials, labels, blocksums);
        finalize_s2<<<1, 64, 0, stream>>>(blocksums, (float*)d_out);
    } else if (ws_size >= WS_NEED1) {
        float* rowacc = (float*)d_ws;
        hipMemsetAsync(rowacc, 0, (size_t)BTOK * 5 * sizeof(float), stream);
        unsigned short* blob = (unsigned short*)((char*)d_ws + WS_BLOB_OFF);
        convert_pack<<<2048, 256, 0, stream>>>(s_in, s_w, t_in, t_w, blob);
        fused_gemm<<<NBLK, 256, 0, stream>>>(blob, labels, rowacc);
        finalize<<<1, 256, 0, stream>>>(rowacc, labels, (float*)d_out);
    } else {
        float* rowacc = (float*)d_ws;
        hipMemsetAsync(rowacc, 0, (size_t)BTOK * 5 * sizeof(float), stream);
        fused_fwd_fb<<<NBLK, 256, 0, stream>>>(s_in, s_w, t_in, t_w, labels, rowacc);
        finalize<<<1, 256, 0, stream>>>(rowacc, labels, (float*)d_out);
    }
}

// Round 7
// 295.680 us; speedup vs baseline: 1.8923x; 1.0181x over previous
//
#include <hip/hip_runtime.h>
#include <stdint.h>

#define BTOK 2048
#define HDIM 512
#define VOC  32000
#define BM 128
#define BN 128
#define BK 32                    // K elems per step; fp8 -> 32 B per row-chunk
#define NKT (HDIM / BK)          // 16 K-steps
#define BLOB_B (BM * BK)         // 4096 BYTES per (panel, kt) blob (fp8)
#define NVB (VOC / BN)           // 250
#define NRB (BTOK / BM)          // 16
#define NBLK (NVB * NRB)         // 4000 (fallback grid)
#define VBG 2                    // vocab blocks per strip
#define NVBG (NVB / VBG)         // 125
#define NSTRIP (NVBG * NRB)      // 2000
#define NSLOT (NVBG * 2)         // 250 partial slots

// ws layout (fp8 strip tier):
//   [0, 256)        blocksums
//   [65536, ..)     fp8 blobs: s_in | t_in | s_w | t_w
//   [PART_OFF, ..)  partials[5][NSLOT][BTOK] f32
#define WS_BLOB_OFF 65536
#define INB_B ((size_t)BTOK * HDIM)      // 1,048,576 B
#define WB_B  ((size_t)VOC * HDIM)       // 16,384,000 B
#define BLOB_BYTES (2 * INB_B + 2 * WB_B)        // 34,865,152
#define PART_OFF (WS_BLOB_OFF + BLOB_BYTES)
#define PART_BYTES ((size_t)5 * NSLOT * BTOK * 4)  // 10,240,000
#define WS_NEED2 (PART_OFF + PART_BYTES)           // ~45.2 MB

typedef __attribute__((ext_vector_type(8))) short bf16x8;
typedef __attribute__((ext_vector_type(4))) float f32x4;

__device__ __forceinline__ unsigned short f2b(float f) {
    union { float f; uint32_t u; } x; x.f = f;
    uint32_t u = x.u;
    u += 0x7fffu + ((u >> 16) & 1u);   // RNE (fallback path)
    return (unsigned short)(u >> 16);
}

// ---------------------------------------------------------------------------
// Pass 1: f32 -> fp8 e4m3 blobs, full-BYTE-address XOR swizzle pre-applied:
//   e = (r*32 + cc) ^ ((r&7)<<3)    (involution; same XOR on the ds_read side)
// 8-byte stores are safe: X has bits 3-5 only; for cc%8==0 and i<8 the byte
// run stays contiguous (bit3 of the base is constant over the run).
// ---------------------------------------------------------------------------
__global__ __launch_bounds__(256) void convert_pack(
    const float* __restrict__ s_in, const float* __restrict__ s_w,
    const float* __restrict__ t_in, const float* __restrict__ t_w,
    unsigned char* __restrict__ blob)
{
    unsigned char* sinb = blob;
    unsigned char* tinb = blob + INB_B;
    unsigned char* swb  = blob + 2 * INB_B;
    unsigned char* twb  = blob + 2 * INB_B + WB_B;
    const int total8 = (2 * BTOK + 2 * VOC) * (HDIM / 8);   // 8 floats / thread-item
    for (int f = blockIdx.x * 256 + threadIdx.x; f < total8; f += gridDim.x * 256) {
        const int row = f >> 6;            // 64 groups of 8 per source row
        const int c8i = f & 63;
        const float* src; unsigned char* dstb; int lrow;
        if (row < BTOK)                { src = s_in; dstb = sinb; lrow = row; }
        else if (row < BTOK + VOC)     { src = s_w;  dstb = swb;  lrow = row - BTOK; }
        else if (row < 2*BTOK + VOC)   { src = t_in; dstb = tinb; lrow = row - (BTOK + VOC); }
        else                           { src = t_w;  dstb = twb;  lrow = row - (2*BTOK + VOC); }
        const float* sp = src + (size_t)lrow * HDIM + c8i * 8;
        const float4 v0 = *reinterpret_cast<const float4*>(sp);
        const float4 v1 = *reinterpret_cast<const float4*>(sp + 4);
        const int p = lrow >> 7, r = lrow & 127;
        const int cc = c8i * 8, kt = cc >> 5, ccm = cc & 31;
        const int e = (r * BK + ccm) ^ ((r & 7) << 3);
        // HW OCP-e4m3 pack (gfx950): 2 floats -> 2 bytes per call
        uint32_t w0 = 0, w1 = 0;
        w0 = __builtin_amdgcn_cvt_pk_fp8_f32(v0.x, v0.y, w0, false);
        w0 = __builtin_amdgcn_cvt_pk_fp8_f32(v0.z, v0.w, w0, true);
        w1 = __builtin_amdgcn_cvt_pk_fp8_f32(v1.x, v1.y, w1, false);
        w1 = __builtin_amdgcn_cvt_pk_fp8_f32(v1.z, v1.w, w1, true);
        uint2 pk; pk.x = w0; pk.y = w1;
        *reinterpret_cast<uint2*>(dstb + (size_t)(p * NKT + kt) * BLOB_B + e) = pk;
    }
}

__device__ __forceinline__ void gl_lds16(const unsigned char* g, unsigned char* l) {
    __builtin_amdgcn_global_load_lds(
        (__attribute__((address_space(1))) const void*)g,
        (__attribute__((address_space(3))) void*)l, 16, 0, 0);
}

// One gl_lds16 per panel per thread (4096 B / 256 thr = 16 B).
#define STAGE(KT, B)                                                          \
    {                                                                         \
        const size_t kb = (size_t)(KT) * BLOB_B;                              \
        const int off = tid * 16;                                             \
        gl_lds16(g0 + kb + off, &smem[B][0][off]);                            \
        gl_lds16(g1 + kb + off, &smem[B][1][off]);                            \
        gl_lds16(g2 + kb + off, &smem[B][2][off]);                            \
        gl_lds16(g3 + kb + off, &smem[B][3][off]);                            \
    }

// fp8 fragments: i64 (8 B) per A/B operand; same (row=l&15, k=(l>>4)*8+i)
// mapping family as the validated bf16 16x16x32 path.
#define COMPUTE(B)                                                            \
    {                                                                         \
        long af[4], bfr[4];                                                   \
        _Pragma("unroll")                                                     \
        for (int mi = 0; mi < 4; ++mi)                                        \
            af[mi] = *reinterpret_cast<const long*>(                          \
                &smem[B][0][((wm + mi * 16 + lr) * BK + lg * 8) ^ xorv]);     \
        _Pragma("unroll")                                                     \
        for (int ni = 0; ni < 4; ++ni)                                        \
            bfr[ni] = *reinterpret_cast<const long*>(                         \
                &smem[B][1][((wn + ni * 16 + lr) * BK + lg * 8) ^ xorv]);     \
        _Pragma("unroll")                                                     \
        for (int mi = 0; mi < 4; ++mi)                                        \
            _Pragma("unroll")                                                 \
            for (int ni = 0; ni < 4; ++ni)                                    \
                acc_s[mi][ni] = __builtin_amdgcn_mfma_f32_16x16x32_fp8_fp8(   \
                    af[mi], bfr[ni], acc_s[mi][ni], 0, 0, 0);                 \
        _Pragma("unroll")                                                     \
        for (int mi = 0; mi < 4; ++mi)                                        \
            af[mi] = *reinterpret_cast<const long*>(                          \
                &smem[B][2][((wm + mi * 16 + lr) * BK + lg * 8) ^ xorv]);     \
        _Pragma("unroll")                                                     \
        for (int ni = 0; ni < 4; ++ni)                                        \
            bfr[ni] = *reinterpret_cast<const long*>(                         \
                &smem[B][3][((wn + ni * 16 + lr) * BK + lg * 8) ^ xorv]);     \
        _Pragma("unroll")                                                     \
        for (int mi = 0; mi < 4; ++mi)                                        \
            _Pragma("unroll")                                                 \
            for (int ni = 0; ni < 4; ++ni)                                    \
                acc_t[mi][ni] = __builtin_amdgcn_mfma_f32_16x16x32_fp8_fp8(   \
                    af[mi], bfr[ni], acc_t[mi][ni], 0, 0, 0);                 \
    }

// Counted vmcnt (T4): 4 loads per STAGE -> vmcnt(4) waits exactly the
// current buffer's loads; next buffer's stay in flight across the barrier.
#define STEP(KT, B)                                                           \
    {                                                                         \
        if ((KT) + 1 < NKT) {                                                 \
            STAGE((KT) + 1, (B) ^ 1);                                         \
            asm volatile("s_waitcnt vmcnt(4)" ::: "memory");                  \
        } else {                                                              \
            asm volatile("s_waitcnt vmcnt(0)" ::: "memory");                  \
        }                                                                     \
        __builtin_amdgcn_sched_barrier(0);                                    \
        __builtin_amdgcn_s_barrier();                                         \
        COMPUTE(B);                                                           \
        __builtin_amdgcn_s_barrier();                                         \
    }

// ---------------------------------------------------------------------------
// Strip GEMM (fp8): (row-block, 2 vocab-blocks) per block; register loss
// partials; one non-atomic partials write per block.
// ---------------------------------------------------------------------------
__global__ __launch_bounds__(256, 2) void fused_gemm_strip(
    const unsigned char* __restrict__ blob,
    const int* __restrict__ labels, float* __restrict__ partials)
{
    __shared__ __align__(16) unsigned char smem[2][4][BLOB_B];   // 32 KB
    __shared__ int lbl[BM];
    const unsigned char* sinb = blob;
    const unsigned char* tinb = blob + INB_B;
    const unsigned char* swb  = blob + 2 * INB_B;
    const unsigned char* twb  = blob + 2 * INB_B + WB_B;

    const int tid = threadIdx.x;
    const int orig = blockIdx.x;
    const int swz  = (orig & 7) * (NSTRIP / 8) + (orig >> 3);   // XCD-bijective
    const int vbg = swz >> 4, rb = swz & 15;
    const int row0 = rb * BM;
    if (tid < BM) lbl[tid] = labels[row0 + tid];

    const int lane = tid & 63, wave = tid >> 6;
    const int wm = (wave >> 1) * 64, wn = (wave & 1) * 64;
    const int lr = lane & 15, lg = lane >> 4;
    const int xorv = (lr & 7) << 3;

    const unsigned char* g0 = sinb + (size_t)(rb * NKT) * BLOB_B;
    const unsigned char* g2 = tinb + (size_t)(rb * NKT) * BLOB_B;

    float pes[4][4] = {}, pdt[4][4] = {}, pss[4][4] = {}, ptt[4][4] = {}, psl[4][4] = {};

    for (int g = 0; g < VBG; ++g) {
        const int vb = vbg * VBG + g;
        const int n0 = vb * BN;
        const unsigned char* g1 = swb + (size_t)(vb * NKT) * BLOB_B;
        const unsigned char* g3 = twb + (size_t)(vb * NKT) * BLOB_B;

        f32x4 acc_s[4][4] = {};
        f32x4 acc_t[4][4] = {};

        STAGE(0, 0);
#pragma unroll 2
        for (int kt = 0; kt < NKT; kt += 2) {
            STEP(kt, 0);
            STEP(kt + 1, 1);
        }

        // D layout: col = lane&15, row = (lane>>4)*4 + reg (m89-verified)
#pragma unroll
        for (int mi = 0; mi < 4; ++mi) {
#pragma unroll
            for (int rg_ = 0; rg_ < 4; ++rg_) {
                const int rloc = wm + mi * 16 + lg * 4 + rg_;
                const int lab = lbl[rloc];
#pragma unroll
                for (int ni = 0; ni < 4; ++ni) {
                    const float s = acc_s[mi][ni][rg_];
                    const float t = acc_t[mi][ni][rg_];
                    pes[mi][rg_] += __expf(s);
                    pdt[mi][rg_] += s * t;
                    pss[mi][rg_] += s * s;
                    ptt[mi][rg_] += t * t;
                    if (n0 + wn + ni * 16 + lr == lab) psl[mi][rg_] += s;
                }
            }
        }
    }

    const int slot = vbg * 2 + (wave & 1);
#pragma unroll
    for (int mi = 0; mi < 4; ++mi) {
#pragma unroll
        for (int rg_ = 0; rg_ < 4; ++rg_) {
            float es = pes[mi][rg_], dt = pdt[mi][rg_], ss = pss[mi][rg_];
            float tt = ptt[mi][rg_], sl = psl[mi][rg_];
#pragma unroll
            for (int m = 1; m < 16; m <<= 1) {
                es += __shfl_xor(es, m, 64);
                dt += __shfl_xor(dt, m, 64);
                ss += __shfl_xor(ss, m, 64);
                tt += __shfl_xor(tt, m, 64);
                sl += __shfl_xor(sl, m, 64);
            }
            if (lr == 0) {
                const int row = row0 + wm + mi * 16 + lg * 4 + rg_;
                partials[(size_t)(0 * NSLOT + slot) * BTOK + row] = es;
                partials[(size_t)(1 * NSLOT + slot) * BTOK + row] = dt;
                partials[(size_t)(2 * NSLOT + slot) * BTOK + row] = ss;
                partials[(size_t)(3 * NSLOT + slot) * BTOK + row] = tt;
                partials[(size_t)(4 * NSLOT + slot) * BTOK + row] = sl;
            }
        }
    }
}

// ---------------------------------------------------------------------------
// finalize stage 1: 32 blocks x 64 rows; reduce 250 slots (coalesced).
// ---------------------------------------------------------------------------
__global__ __launch_bounds__(256) void finalize_s1(
    const float* __restrict__ partials, const int* __restrict__ labels,
    float* __restrict__ blocksums)
{
    __shared__ float fsum[4][64][5];
    const int t = threadIdx.x, b = blockIdx.x;
    const int rl = t & 63, w = t >> 6;
    const int row = b * 64 + rl;
    float a0 = 0.f, a1 = 0.f, a2 = 0.f, a3 = 0.f, a4 = 0.f;
    for (int slot = w; slot < NSLOT; slot += 4) {
        const size_t base = (size_t)slot * BTOK + row;
        a0 += partials[(size_t)0 * NSLOT * BTOK + base];
        a1 += partials[(size_t)1 * NSLOT * BTOK + base];
        a2 += partials[(size_t)2 * NSLOT * BTOK + base];
        a3 += partials[(size_t)3 * NSLOT * BTOK + base];
        a4 += partials[(size_t)4 * NSLOT * BTOK + base];
    }
    fsum[w][rl][0] = a0; fsum[w][rl][1] = a1; fsum[w][rl][2] = a2;
    fsum[w][rl][3] = a3; fsum[w][rl][4] = a4;
    __syncthreads();
    if (t < 64) {
        const float es = fsum[0][t][0] + fsum[1][t][0] + fsum[2][t][0] + fsum[3][t][0];
        const float dt = fsum[0][t][1] + fsum[1][t][1] + fsum[2][t][1] + fsum[3][t][1];
        const float ss = fsum[0][t][2] + fsum[1][t][2] + fsum[2][t][2] + fsum[3][t][2];
        const float tt = fsum[0][t][3] + fsum[1][t][3] + fsum[2][t][3] + fsum[3][t][3];
        const float sl = fsum[0][t][4] + fsum[1][t][4] + fsum[2][t][4] + fsum[3][t][4];
        float hard = 0.f, soft;
        if (labels[row] != -100) hard = logf(es) - sl;
        const float ns = fmaxf(sqrtf(ss), 1e-12f);
        const float nt = fmaxf(sqrtf(tt), 1e-12f);
        soft = 1.f - dt / (ns * nt);
#pragma unroll
        for (int m = 1; m < 64; m <<= 1) {
            hard += __shfl_xor(hard, m, 64);
            soft += __shfl_xor(soft, m, 64);
        }
        if (t == 0) {
            blocksums[b * 2 + 0] = hard;
            blocksums[b * 2 + 1] = soft;
        }
    }
}

__global__ void finalize_s2(const float* __restrict__ blocksums,
                            float* __restrict__ out)
{
    const int t = threadIdx.x;   // 64
    float hard = (t < 32) ? blocksums[t * 2 + 0] : 0.f;
    float soft = (t < 32) ? blocksums[t * 2 + 1] : 0.f;
#pragma unroll
    for (int m = 1; m < 64; m <<= 1) {
        hard += __shfl_xor(hard, m, 64);
        soft += __shfl_xor(soft, m, 64);
    }
    if (t == 0)
        out[0] = 0.5f * (hard / (float)BTOK) + 0.25f * (soft / (float)BTOK);
}

// ---------------------------------------------------------------------------
// Fallback (ws too small): R2's validated bf16 fused-conversion kernel.
// ---------------------------------------------------------------------------
#define BKF 32
#define NKTF (HDIM / BKF)
#define TILE_EF (BM * BKF)

__device__ __forceinline__ int swz_e32(int r, int c) {
    return (r * BKF + c) ^ ((r & 7) << 3);
}

__global__ __launch_bounds__(256, 2) void fused_fwd_fb(
    const float* __restrict__ s_in, const float* __restrict__ s_w,
    const float* __restrict__ t_in, const float* __restrict__ t_w,
    const int* __restrict__ labels, float* __restrict__ rowacc)
{
    __shared__ unsigned short smem[2][4][TILE_EF];
    __shared__ int lbl[BM];
    const int tid = threadIdx.x;
    const int orig = blockIdx.x;
    const int swz  = (orig & 7) * (NBLK / 8) + (orig >> 3);
    const int vb = swz >> 4, rb = swz & 15;
    const int n0 = vb * BN, row0 = rb * BM;
    if (tid < BM) lbl[tid] = labels[row0 + tid];
    const int rr = tid >> 3, c8 = tid & 7;
    const float* srcp[4];
    srcp[0] = s_in + (size_t)(row0 + rr) * HDIM + c8 * 4;
    srcp[1] = s_w  + (size_t)(n0   + rr) * HDIM + c8 * 4;
    srcp[2] = t_in + (size_t)(row0 + rr) * HDIM + c8 * 4;
    srcp[3] = t_w  + (size_t)(n0   + rr) * HDIM + c8 * 4;
    f32x4 acc_s[4][4] = {}, acc_t[4][4] = {};
    const int lane = tid & 63, wave = tid >> 6;
    const int wm = (wave >> 1) * 64, wn = (wave & 1) * 64;
    const int lr = lane & 15, lg = lane >> 4;
    const int ec = lg * 8;
    float4 rg[4][4];

#define LOADS_FB(KT)                                                          \
    { const int k0 = (KT) * BKF;                                              \
      _Pragma("unroll") for (int t = 0; t < 4; ++t)                           \
      _Pragma("unroll") for (int it = 0; it < 4; ++it)                        \
          rg[t][it] = *reinterpret_cast<const float4*>(srcp[t] + (size_t)it * 32 * HDIM + k0); }
#define CVT_WRITE_FB(B)                                                       \
    { _Pragma("unroll") for (int t = 0; t < 4; ++t)                           \
      _Pragma("unroll") for (int it = 0; it < 4; ++it) {                      \
          const int r = rr + it * 32;                                         \
          ushort4 h;                                                          \
          h.x = f2b(rg[t][it].x); h.y = f2b(rg[t][it].y);                     \
          h.z = f2b(rg[t][it].z); h.w = f2b(rg[t][it].w);                     \
          *reinterpret_cast<ushort4*>(&smem[B][t][swz_e32(r, c8 * 4)]) = h; } }
#define COMPUTE_FB(B)                                                         \
    { const unsigned short* As = smem[B][0]; const unsigned short* Bs = smem[B][1]; \
      const unsigned short* At = smem[B][2]; const unsigned short* Bt = smem[B][3]; \
      bf16x8 af[4], bfr[4];                                                   \
      _Pragma("unroll") for (int mi = 0; mi < 4; ++mi)                        \
          af[mi] = *reinterpret_cast<const bf16x8*>(As + swz_e32(wm + mi * 16 + lr, ec)); \
      _Pragma("unroll") for (int ni = 0; ni < 4; ++ni)                        \
          bfr[ni] = *reinterpret_cast<const bf16x8*>(Bs + swz_e32(wn + ni * 16 + lr, ec)); \
      _Pragma("unroll") for (int mi = 0; mi < 4; ++mi)                        \
      _Pragma("unroll") for (int ni = 0; ni < 4; ++ni)                        \
          acc_s[mi][ni] = __builtin_amdgcn_mfma_f32_16x16x32_bf16(af[mi], bfr[ni], acc_s[mi][ni], 0, 0, 0); \
      _Pragma("unroll") for (int mi = 0; mi < 4; ++mi)                        \
          af[mi] = *reinterpret_cast<const bf16x8*>(At + swz_e32(wm + mi * 16 + lr, ec)); \
      _Pragma("unroll") for (int ni = 0; ni < 4; ++ni)                        \
          bfr[ni] = *reinterpret_cast<const bf16x8*>(Bt + swz_e32(wn + ni * 16 + lr, ec)); \
      _Pragma("unroll") for (int mi = 0; mi < 4; ++mi)                        \
      _Pragma("unroll") for (int ni = 0; ni < 4; ++ni)                        \
          acc_t[mi][ni] = __builtin_amdgcn_mfma_f32_16x16x32_bf16(af[mi], bfr[ni], acc_t[mi][ni], 0, 0, 0); }

    LOADS_FB(0); CVT_WRITE_FB(0); __syncthreads();
    int cur = 0;
#pragma unroll 2
    for (int kt = 0; kt < NKTF; ++kt) {
        if (kt + 1 < NKTF) LOADS_FB(kt + 1);
        COMPUTE_FB(cur);
        if (kt + 1 < NKTF) CVT_WRITE_FB(cur ^ 1);
        __syncthreads();
        cur ^= 1;
    }
#undef LOADS_FB
#undef CVT_WRITE_FB
#undef COMPUTE_FB
#pragma unroll
    for (int mi = 0; mi < 4; ++mi) {
#pragma unroll
        for (int rg_ = 0; rg_ < 4; ++rg_) {
            const int rloc = wm + mi * 16 + lg * 4 + rg_;
            const int lab = lbl[rloc];
            float es = 0.f, dt = 0.f, ss = 0.f, tt = 0.f, sl = 0.f;
#pragma unroll
            for (int ni = 0; ni < 4; ++ni) {
                const float s = acc_s[mi][ni][rg_];
                const float t = acc_t[mi][ni][rg_];
                es += __expf(s); dt += s * t; ss += s * s; tt += t * t;
                if (n0 + wn + ni * 16 + lr == lab) sl += s;
            }
#pragma unroll
            for (int m = 1; m < 16; m <<= 1) {
                es += __shfl_xor(es, m, 64); dt += __shfl_xor(dt, m, 64);
                ss += __shfl_xor(ss, m, 64); tt += __shfl_xor(tt, m, 64);
                sl += __shfl_xor(sl, m, 64);
            }
            if (lr == 0) {
                float* ra = rowacc + (size_t)(row0 + rloc) * 5;
                atomicAdd(ra + 0, es); atomicAdd(ra + 1, dt); atomicAdd(ra + 2, ss);
                atomicAdd(ra + 3, tt); atomicAdd(ra + 4, sl);
            }
        }
    }
}

__global__ __launch_bounds__(256) void finalize(const float* __restrict__ rowacc,
                                                const int* __restrict__ labels,
                                                float* __restrict__ out)
{
    const int tid = threadIdx.x;
    float hard = 0.f, soft = 0.f;
    for (int r = tid; r < BTOK; r += 256) {
        const float* ra = rowacc + (size_t)r * 5;
        const float es = ra[0], dt = ra[1], ss = ra[2], tt = ra[3], sl = ra[4];
        if (labels[r] != -100) hard += logf(es) - sl;
        const float ns = fmaxf(sqrtf(ss), 1e-12f);
        const float nt = fmaxf(sqrtf(tt), 1e-12f);
        soft += 1.f - dt / (ns * nt);
    }
#pragma unroll
    for (int m = 1; m < 64; m <<= 1) {
        hard += __shfl_xor(hard, m, 64);
        soft += __shfl_xor(soft, m, 64);
    }
    __shared__ float sh[2][4];
    const int w = tid >> 6;
    if ((tid & 63) == 0) { sh[0][w] = hard; sh[1][w] = soft; }
    __syncthreads();
    if (tid == 0) {
        const float h = sh[0][0] + sh[0][1] + sh[0][2] + sh[0][3];
        const float s = sh[1][0] + sh[1][1] + sh[1][2] + sh[1][3];
        out[0] = 0.5f * (h / (float)BTOK) + 0.5f * (0.5f * s / (float)BTOK);
    }
}

extern "C" void kernel_launch(void* const* d_in, const int* in_sizes, int n_in,
                              void* d_out, int out_size, void* d_ws, size_t ws_size,
                              hipStream_t stream)
{
    const float* s_in   = (const float*)d_in[0];
    const float* s_w    = (const float*)d_in[1];
    const float* t_in   = (const float*)d_in[2];
    const float* t_w    = (const float*)d_in[3];
    const int*   labels = (const int*)d_in[4];

    if (ws_size >= WS_NEED2) {
        unsigned char* blob = (unsigned char*)d_ws + WS_BLOB_OFF;
        float* partials  = (float*)((char*)d_ws + PART_OFF);
        float* blocksums = (float*)d_ws;
        convert_pack<<<2048, 256, 0, stream>>>(s_in, s_w, t_in, t_w, blob);
        fused_gemm_strip<<<NSTRIP, 256, 0, stream>>>(blob, labels, partials);
        finalize_s1<<<BTOK / 64, 256, 0, stream>>>(partials, labels, blocksums);
        finalize_s2<<<1, 64, 0, stream>>>(blocksums, (float*)d_out);
    } else {
        float* rowacc = (float*)d_ws;
        hipMemsetAsync(rowacc, 0, (size_t)BTOK * 5 * sizeof(float), stream);
        fused_fwd_fb<<<NBLK, 256, 0, stream>>>(s_in, s_w, t_in, t_w, labels, rowacc);
        finalize<<<1, 256, 0, stream>>>(rowacc, labels, (float*)d_out);
    }
}